// Round 3
// baseline (2010.526 us; speedup 1.0000x reference)
//
#include <hip/hip_runtime.h>

// SNN forward: T=20, B=65536, F=16; layers 16->128->128->64->10, LIF with
// beta=0.9, thr=1.0, reset-by-subtraction. fp32 throughout, bit-exact vs
// XLA-CPU hypothesis: ascending-k fmaf chains for dots, uncontracted
// ((0.9*m)+c)-r elementwise, strict > compares.

namespace {
constexpr int kB = 65536;
constexpr int kT = 20;
}

// Ascending-k fused chain; named to avoid macro-hygiene collisions with .w
__device__ __forceinline__ float fma4(const float4 s, const float4 wv, float acc) {
  acc = fmaf(s.x, wv.x, acc);
  acc = fmaf(s.y, wv.y, acc);
  acc = fmaf(s.z, wv.z, acc);
  acc = fmaf(s.w, wv.w, acc);
  return acc;
}

__global__ __launch_bounds__(1024) void snn_fwd(
    const float* __restrict__ x,
    const float* __restrict__ gw1,
    const float* __restrict__ gw2,
    const float* __restrict__ gw3,
    const float* __restrict__ gw4,
    float* __restrict__ out)
{
#pragma clang fp contract(off)
  // Weights staged in LDS, XOR-swizzled per 16B block so per-lane row reads
  // (stride 512B) are bank-conflict-free.  126.5 KB total (<160 KB/CU).
  __shared__ __align__(16) float w1s[128 * 16];
  __shared__ __align__(16) float w2s[128 * 128];
  __shared__ __align__(16) float w3s[64 * 128];
  __shared__ __align__(16) float w4s[10 * 64];
  __shared__ __align__(16) float spks[16][320];  // per wave: spk1[128] spk2[128] spk3[64]

  const int tid = threadIdx.x;

  for (int i = tid; i < 128 * 16; i += 1024) {
    int j = i >> 4, k = i & 15;
    w1s[(j << 4) + ((((k >> 2) ^ j) & 3) << 2) + (k & 3)] = gw1[i];
  }
  for (int i = tid; i < 128 * 128; i += 1024) {
    int j = i >> 7, k = i & 127;
    w2s[(j << 7) + ((((k >> 2) ^ j) & 31) << 2) + (k & 3)] = gw2[i];
  }
  for (int i = tid; i < 64 * 128; i += 1024) {
    int j = i >> 7, k = i & 127;
    w3s[(j << 7) + ((((k >> 2) ^ j) & 31) << 2) + (k & 3)] = gw3[i];
  }
  for (int i = tid; i < 640; i += 1024) w4s[i] = gw4[i];
  __syncthreads();

  const int lane = tid & 63;
  const int wv = tid >> 6;
  const int gw = (blockIdx.x << 4) + wv;  // 4096 waves total

  float* __restrict__ spk1 = &spks[wv][0];
  float* __restrict__ spk2 = &spks[wv][128];
  float* __restrict__ spk3 = &spks[wv][256];

  const int s32 = lane & 31;  // (64+lane)&31 == lane&31: same swizzle both rows
  const int s4w = lane & 3;
  const float4* __restrict__ r1a = reinterpret_cast<const float4*>(w1s + (lane << 4));
  const float4* __restrict__ r1b = reinterpret_cast<const float4*>(w1s + ((64 + lane) << 4));
  const float4* __restrict__ r2a = reinterpret_cast<const float4*>(w2s + (lane << 7));
  const float4* __restrict__ r2b = reinterpret_cast<const float4*>(w2s + ((64 + lane) << 7));
  const float4* __restrict__ r3  = reinterpret_cast<const float4*>(w3s + (lane << 7));
  const float4* __restrict__ r4  = reinterpret_cast<const float4*>(w4s + ((lane < 10 ? lane : 0) << 6));

  for (int b = gw; b < kB; b += 4096) {
    float m1a = 0.f, m1b = 0.f, m2a = 0.f, m2b = 0.f, m3v = 0.f, m4v = 0.f;
    for (int t = 0; t < kT; ++t) {
      const float4* xp = reinterpret_cast<const float4*>(x + (((size_t)t * kB + b) << 4));
      float4 xa = xp[0], xb = xp[1], xc = xp[2], xd = xp[3];

      // ---------------- layer 1 (K=16, real x): ascending-k fmaf chain
      float ca = 0.f, cb = 0.f;
      ca = fma4(xa, r1a[0 ^ s4w], ca);
      ca = fma4(xb, r1a[1 ^ s4w], ca);
      ca = fma4(xc, r1a[2 ^ s4w], ca);
      ca = fma4(xd, r1a[3 ^ s4w], ca);
      cb = fma4(xa, r1b[0 ^ s4w], cb);
      cb = fma4(xb, r1b[1 ^ s4w], cb);
      cb = fma4(xc, r1b[2 ^ s4w], cb);
      cb = fma4(xd, r1b[3 ^ s4w], cb);

      // LIF1 (uncontracted: ((0.9*m)+c)-r)
      float rs1a = m1a > 1.0f ? 1.0f : 0.0f;
      m1a = (0.9f * m1a + ca) - rs1a;
      float s1a = m1a > 1.0f ? 1.0f : 0.0f;
      float rs1b = m1b > 1.0f ? 1.0f : 0.0f;
      m1b = (0.9f * m1b + cb) - rs1b;
      float s1b = m1b > 1.0f ? 1.0f : 0.0f;
      spk1[lane] = s1a;
      spk1[64 + lane] = s1b;

      // ---------------- layer 2 (K=128, binary spikes)
      float a2a = 0.f, a2b = 0.f;
      {
        const float4* sp = reinterpret_cast<const float4*>(spk1);
#pragma unroll 8
        for (int k4 = 0; k4 < 32; ++k4) {
          float4 s = sp[k4];                    // broadcast read (uniform value)
          if (s.x + s.y + s.z + s.w > 0.f) {    // wave-uniform skip of dead chunks
            a2a = fma4(s, r2a[k4 ^ s32], a2a);
            a2b = fma4(s, r2b[k4 ^ s32], a2b);
          }
        }
      }
      float rs2a = m2a > 1.0f ? 1.0f : 0.0f;
      m2a = (0.9f * m2a + a2a) - rs2a;
      float s2a = m2a > 1.0f ? 1.0f : 0.0f;
      float rs2b = m2b > 1.0f ? 1.0f : 0.0f;
      m2b = (0.9f * m2b + a2b) - rs2b;
      float s2b = m2b > 1.0f ? 1.0f : 0.0f;
      spk2[lane] = s2a;
      spk2[64 + lane] = s2b;

      // ---------------- layer 3 (64 neurons, K=128)
      float a3 = 0.f;
      {
        const float4* sp = reinterpret_cast<const float4*>(spk2);
#pragma unroll 8
        for (int k4 = 0; k4 < 32; ++k4) {
          float4 s = sp[k4];
          if (s.x + s.y + s.z + s.w > 0.f) {
            a3 = fma4(s, r3[k4 ^ s32], a3);
          }
        }
      }
      float rs3 = m3v > 1.0f ? 1.0f : 0.0f;
      m3v = (0.9f * m3v + a3) - rs3;
      float s3 = m3v > 1.0f ? 1.0f : 0.0f;
      spk3[lane] = s3;

      // ---------------- layer 4 (10 neurons on lanes 0..9, K=64)
      if (lane < 10) {
        float a4 = 0.f;
        const float4* sp = reinterpret_cast<const float4*>(spk3);
#pragma unroll
        for (int k4 = 0; k4 < 16; ++k4) {
          a4 = fma4(sp[k4], r4[k4], a4);  // unswizzled (10 lanes, negligible)
        }
        float rs4 = m4v > 1.0f ? 1.0f : 0.0f;
        m4v = (0.9f * m4v + a4) - rs4;
        float s4 = m4v > 1.0f ? 1.0f : 0.0f;
        out[((size_t)t * kB + b) * 10 + lane] = s4;
      }
    }
  }
}

extern "C" void kernel_launch(void* const* d_in, const int* in_sizes, int n_in,
                              void* d_out, int out_size, void* d_ws, size_t ws_size,
                              hipStream_t stream) {
  const float* x   = (const float*)d_in[0];
  const float* w1  = (const float*)d_in[1];
  const float* w2  = (const float*)d_in[2];
  const float* w3  = (const float*)d_in[3];
  const float* w4  = (const float*)d_in[4];
  float* out = (float*)d_out;
  snn_fwd<<<dim3(256), dim3(1024), 0, stream>>>(x, w1, w2, w3, w4, out);
}

// Round 4
// 1147.303 us; speedup vs baseline: 1.7524x; 1.7524x over previous
//
#include <hip/hip_runtime.h>

// SNN forward: T=20, B=65536, F=16; layers 16->128->128->64->10, LIF beta=0.9,
// thr=1.0, reset-subtract. Bit-exact vs XLA-CPU (verified r3: absmax=0):
// ascending-k fmaf dot chains, uncontracted ((0.9*m)+c)-r, strict > compares.
// r4: S=8 batch elems/wave amortize LDS weight reads; spikes as __ballot
// masks in SGPRs; sparse layers apply spikes as conditional adds
// (fmaf(1,w,a)=a+w, fmaf(0,w,a)=a -- exactly equal to the fma chain).

namespace {
constexpr int kB = 65536;
constexpr int kT = 20;
constexpr int S = 8;   // batch elements per wave
}

__device__ __forceinline__ float fma4(const float4 s, const float4 wv, float acc) {
  acc = fmaf(s.x, wv.x, acc);
  acc = fmaf(s.y, wv.y, acc);
  acc = fmaf(s.z, wv.z, acc);
  acc = fmaf(s.w, wv.w, acc);
  return acc;
}

__global__ __launch_bounds__(1024, 4) void snn_fwd(
    const float* __restrict__ x,
    const float* __restrict__ gw1,
    const float* __restrict__ gw2,
    const float* __restrict__ gw3,
    const float* __restrict__ gw4,
    float* __restrict__ out)
{
#pragma clang fp contract(off)
  // Block-swizzled weight staging (verified r3): row j, 16B-chunk k stored at
  // chunk (k ^ j) & (chunks-1) -> per-lane row reads at stride 512B are
  // conflict-free.  106.5 KB LDS.
  __shared__ __align__(16) float w1s[128 * 16];
  __shared__ __align__(16) float w2s[128 * 128];
  __shared__ __align__(16) float w3s[64 * 128];
  __shared__ __align__(16) float w4s[10 * 64];

  const int tid = threadIdx.x;

  for (int i = tid; i < 128 * 16; i += 1024) {
    int j = i >> 4, k = i & 15;
    w1s[(j << 4) + ((((k >> 2) ^ j) & 3) << 2) + (k & 3)] = gw1[i];
  }
  for (int i = tid; i < 128 * 128; i += 1024) {
    int j = i >> 7, k = i & 127;
    w2s[(j << 7) + ((((k >> 2) ^ j) & 31) << 2) + (k & 3)] = gw2[i];
  }
  for (int i = tid; i < 64 * 128; i += 1024) {
    int j = i >> 7, k = i & 127;
    w3s[(j << 7) + ((((k >> 2) ^ j) & 31) << 2) + (k & 3)] = gw3[i];
  }
  for (int i = tid; i < 640; i += 1024) w4s[i] = gw4[i];
  __syncthreads();

  const int lane = tid & 63;
  const int wv = tid >> 6;
  const int gwv = (blockIdx.x << 4) + wv;  // 4096 waves

  const int s32 = lane & 31;
  const int s4w = lane & 3;
  const float4* __restrict__ r1a = reinterpret_cast<const float4*>(w1s + (lane << 4));
  const float4* __restrict__ r1b = reinterpret_cast<const float4*>(w1s + ((64 + lane) << 4));
  const float4* __restrict__ r2a = reinterpret_cast<const float4*>(w2s + (lane << 7));
  const float4* __restrict__ r2b = reinterpret_cast<const float4*>(w2s + ((64 + lane) << 7));
  const float4* __restrict__ r3  = reinterpret_cast<const float4*>(w3s + (lane << 7));
  const float*  __restrict__ r4f = w4s + ((lane < 10 ? lane : 0) << 6);

  for (int g = 0; g < 2; ++g) {
    const int bg = (gwv << 3) + (g << 15);  // base batch index of this 8-group

    float m1a[S], m1b[S], m2a[S], m2b[S], m3v[S], m4v[S];
#pragma unroll
    for (int s = 0; s < S; ++s) {
      m1a[s] = 0.f; m1b[s] = 0.f; m2a[s] = 0.f; m2b[s] = 0.f; m3v[s] = 0.f; m4v[s] = 0.f;
    }

    for (int t = 0; t < kT; ++t) {
      const float4* __restrict__ xbase =
          reinterpret_cast<const float4*>(x + ((size_t)t * kB + bg) * 16);

      // ---------------- layer 1: dense fmaf, weights amortized over S
      float ca[S], cb[S];
#pragma unroll
      for (int s = 0; s < S; ++s) { ca[s] = 0.f; cb[s] = 0.f; }
#pragma unroll
      for (int c = 0; c < 4; ++c) {
        float4 wa = r1a[c ^ s4w];
        float4 wb = r1b[c ^ s4w];
#pragma unroll
        for (int s = 0; s < S; ++s) {
          float4 xs = xbase[(s << 2) + c];  // uniform-address load, cache-hit
          ca[s] = fma4(xs, wa, ca[s]);
          cb[s] = fma4(xs, wb, cb[s]);
        }
      }
      unsigned long long mA[S], mB[S];  // spk1 bits: k=0..63 in mA, 64..127 in mB
#pragma unroll
      for (int s = 0; s < S; ++s) {
        float rs = m1a[s] > 1.0f ? 1.0f : 0.0f;
        m1a[s] = (0.9f * m1a[s] + ca[s]) - rs;
        mA[s] = __ballot(m1a[s] > 1.0f);
        float rs2 = m1b[s] > 1.0f ? 1.0f : 0.0f;
        m1b[s] = (0.9f * m1b[s] + cb[s]) - rs2;
        mB[s] = __ballot(m1b[s] > 1.0f);
      }

      // ---------------- layer 2: conditional adds gated by spike bits
      float aa[S], ab[S];
#pragma unroll
      for (int s = 0; s < S; ++s) { aa[s] = 0.f; ab[s] = 0.f; }
#pragma unroll 2
      for (int k4 = 0; k4 < 16; ++k4) {  // k = 0..63
        float4 wa = r2a[k4 ^ s32];
        float4 wb = r2b[k4 ^ s32];
        const int sh = k4 << 2;
#pragma unroll
        for (int s = 0; s < S; ++s) {
          unsigned nib = (unsigned)(mA[s] >> sh) & 15u;
          if (nib) {
            if (nib & 1u) { aa[s] += wa.x; ab[s] += wb.x; }
            if (nib & 2u) { aa[s] += wa.y; ab[s] += wb.y; }
            if (nib & 4u) { aa[s] += wa.z; ab[s] += wb.z; }
            if (nib & 8u) { aa[s] += wa.w; ab[s] += wb.w; }
          }
        }
      }
#pragma unroll 2
      for (int k4 = 16; k4 < 32; ++k4) {  // k = 64..127
        float4 wa = r2a[k4 ^ s32];
        float4 wb = r2b[k4 ^ s32];
        const int sh = (k4 - 16) << 2;
#pragma unroll
        for (int s = 0; s < S; ++s) {
          unsigned nib = (unsigned)(mB[s] >> sh) & 15u;
          if (nib) {
            if (nib & 1u) { aa[s] += wa.x; ab[s] += wb.x; }
            if (nib & 2u) { aa[s] += wa.y; ab[s] += wb.y; }
            if (nib & 4u) { aa[s] += wa.z; ab[s] += wb.z; }
            if (nib & 8u) { aa[s] += wa.w; ab[s] += wb.w; }
          }
        }
      }
      unsigned long long mC[S], mD[S];  // spk2
#pragma unroll
      for (int s = 0; s < S; ++s) {
        float rs = m2a[s] > 1.0f ? 1.0f : 0.0f;
        m2a[s] = (0.9f * m2a[s] + aa[s]) - rs;
        mC[s] = __ballot(m2a[s] > 1.0f);
        float rs2 = m2b[s] > 1.0f ? 1.0f : 0.0f;
        m2b[s] = (0.9f * m2b[s] + ab[s]) - rs2;
        mD[s] = __ballot(m2b[s] > 1.0f);
      }

      // ---------------- layer 3: sparse (spk2 ~5%): OR-skip chunks
      float a3[S];
#pragma unroll
      for (int s = 0; s < S; ++s) a3[s] = 0.f;
      unsigned long long orC = 0ull, orD = 0ull;
#pragma unroll
      for (int s = 0; s < S; ++s) { orC |= mC[s]; orD |= mD[s]; }
#pragma unroll 2
      for (int k4 = 0; k4 < 16; ++k4) {
        const int sh = k4 << 2;
        unsigned onib = (unsigned)(orC >> sh) & 15u;
        if (!onib) continue;
        float4 wc = r3[k4 ^ s32];
#pragma unroll
        for (int s = 0; s < S; ++s) {
          unsigned nib = (unsigned)(mC[s] >> sh) & 15u;
          if (nib) {
            if (nib & 1u) a3[s] += wc.x;
            if (nib & 2u) a3[s] += wc.y;
            if (nib & 4u) a3[s] += wc.z;
            if (nib & 8u) a3[s] += wc.w;
          }
        }
      }
#pragma unroll 2
      for (int k4 = 16; k4 < 32; ++k4) {
        const int sh = (k4 - 16) << 2;
        unsigned onib = (unsigned)(orD >> sh) & 15u;
        if (!onib) continue;
        float4 wc = r3[k4 ^ s32];
#pragma unroll
        for (int s = 0; s < S; ++s) {
          unsigned nib = (unsigned)(mD[s] >> sh) & 15u;
          if (nib) {
            if (nib & 1u) a3[s] += wc.x;
            if (nib & 2u) a3[s] += wc.y;
            if (nib & 4u) a3[s] += wc.z;
            if (nib & 8u) a3[s] += wc.w;
          }
        }
      }
      unsigned long long mE[S];  // spk3 (64 neurons)
#pragma unroll
      for (int s = 0; s < S; ++s) {
        float rs = m3v[s] > 1.0f ? 1.0f : 0.0f;
        m3v[s] = (0.9f * m3v[s] + a3[s]) - rs;
        mE[s] = __ballot(m3v[s] > 1.0f);
      }

      // ---------------- layer 4: very sparse (spk3 ~0.1%): ctz over set bits
#pragma unroll
      for (int s = 0; s < S; ++s) {
        float a4 = 0.f;
        unsigned long long m = mE[s];
        while (m) {  // ascending-k set-bit iteration (exact chain order)
          int k = __builtin_ctzll(m);
          m &= m - 1;
          a4 += r4f[k];  // rare LDS read; lanes>=10 read row 0 harmlessly
        }
        float rs = m4v[s] > 1.0f ? 1.0f : 0.0f;
        m4v[s] = (0.9f * m4v[s] + a4) - rs;
        float s4v = m4v[s] > 1.0f ? 1.0f : 0.0f;
        if (lane < 10) out[((size_t)t * kB + bg + s) * 10 + lane] = s4v;
      }
    }
  }
}

extern "C" void kernel_launch(void* const* d_in, const int* in_sizes, int n_in,
                              void* d_out, int out_size, void* d_ws, size_t ws_size,
                              hipStream_t stream) {
  const float* x   = (const float*)d_in[0];
  const float* w1  = (const float*)d_in[1];
  const float* w2  = (const float*)d_in[2];
  const float* w3  = (const float*)d_in[3];
  const float* w4  = (const float*)d_in[4];
  float* out = (float*)d_out;
  snn_fwd<<<dim3(256), dim3(1024), 0, stream>>>(x, w1, w2, w3, w4, out);
}